// Round 1
// baseline (178.562 us; speedup 1.0000x reference)
//
#include <hip/hip_runtime.h>

#define BB 4
#define NN 10000
#define EE 200000
#define DD 32

__device__ __forceinline__ float fast_tanh(float v) {
    float a = fabsf(v);
    float e = __expf(2.0f * a);            // e^{2|v|}, overflows to +inf for big a -> r = 1
    float r = 1.0f - 2.0f / (e + 1.0f);
    return copysignf(r, v);
}

// One wave (64 lanes) per edge.
// lane l: d = l&31 (output column), h = l>>5; computes batches b=h and b=h+2.
__global__ __launch_bounds__(256) void edge_kernel(
    const float* __restrict__ x,        // (B,N,D)
    const int*   __restrict__ eidx,     // (2,E)
    const float* __restrict__ weight,   // (E,D,D)
    const float* __restrict__ bias,     // (E,D)
    float* __restrict__ sums,           // (B,N,D) accum
    float* __restrict__ cnt)            // (N)
{
    int gid = blockIdx.x * blockDim.x + threadIdx.x;
    int e = gid >> 6;
    if (e >= EE) return;
    int lane = gid & 63;
    int d = lane & 31;
    int h = lane >> 5;

    int src = eidx[e];
    int dst = eidx[EE + e];

    // lane holds x[b, src, d]; broadcast across half-wave in the i-loop
    float xr0 = x[(size_t)h       * NN * DD + (size_t)src * DD + d];
    float xr1 = x[(size_t)(h + 2) * NN * DD + (size_t)src * DD + d];

    const float* __restrict__ W = weight + (size_t)e * DD * DD;
    float acc0 = 0.f, acc1 = 0.f;
#pragma unroll
    for (int i = 0; i < DD; ++i) {
        float w  = W[i * DD + d];          // coalesced: 32 consecutive floats, both halves same line
        float x0 = __shfl(xr0, i, 32);     // x[h,   src, i]
        float x1 = __shfl(xr1, i, 32);     // x[h+2, src, i]
        acc0 = fmaf(x0, w, acc0);
        acc1 = fmaf(x1, w, acc1);
    }
    float bv = bias[(size_t)e * DD + d];
    float o0 = fast_tanh(acc0 + bv);
    float o1 = fast_tanh(acc1 + bv);

    atomicAdd(&sums[(size_t)h       * NN * DD + (size_t)dst * DD + d], o0);
    atomicAdd(&sums[(size_t)(h + 2) * NN * DD + (size_t)dst * DD + d], o1);
    if (lane == 0) atomicAdd(&cnt[dst], 1.0f);
}

// One wave per node: agg = sums/max(cnt,1); state; batch-norm over (B,D)=128 vals.
__global__ __launch_bounds__(256) void node_kernel(
    const float* __restrict__ sums,     // (B,N,D)
    const float* __restrict__ cnt,      // (N)
    const float* __restrict__ state_w,  // (D,1)
    const float* __restrict__ state_b,  // (1)
    const float* __restrict__ bn_gamma, // (N)
    const float* __restrict__ bn_beta,  // (N)
    float* __restrict__ out_state,      // (B,N)
    float* __restrict__ out_bn)         // (B,N,D)
{
    int gid = blockIdx.x * blockDim.x + threadIdx.x;
    int n = gid >> 6;
    if (n >= NN) return;
    int lane = gid & 63;
    int d = lane & 31;
    int h = lane >> 5;

    float inv = 1.0f / fmaxf(cnt[n], 1.0f);
    float v0 = sums[(size_t)h       * NN * DD + (size_t)n * DD + d] * inv;
    float v1 = sums[(size_t)(h + 2) * NN * DD + (size_t)n * DD + d] * inv;

    // state: reduce v*state_w[d] over each half-wave (one batch per half, two passes in regs)
    float sw = state_w[d];
    float s0 = v0 * sw, s1 = v1 * sw;
    #pragma unroll
    for (int m = 16; m >= 1; m >>= 1) {
        s0 += __shfl_xor(s0, m, 32);
        s1 += __shfl_xor(s1, m, 32);
    }
    if (d == 0) {
        float sb = state_b[0];
        out_state[(size_t)h       * NN + n] = s0 + sb;
        out_state[(size_t)(h + 2) * NN + n] = s1 + sb;
    }

    // mean/var over all B*D = 128 values
    float sum = v0 + v1;
    float sq  = v0 * v0 + v1 * v1;
    #pragma unroll
    for (int m = 32; m >= 1; m >>= 1) {
        sum += __shfl_xor(sum, m, 64);
        sq  += __shfl_xor(sq,  m, 64);
    }
    float mean  = sum * (1.0f / 128.0f);
    float var   = sq  * (1.0f / 128.0f) - mean * mean;
    float scale = rsqrtf(var + 1e-5f);
    float g = bn_gamma[n], be = bn_beta[n];

    out_bn[(size_t)h       * NN * DD + (size_t)n * DD + d] = (v0 - mean) * scale * g + be;
    out_bn[(size_t)(h + 2) * NN * DD + (size_t)n * DD + d] = (v1 - mean) * scale * g + be;
}

extern "C" void kernel_launch(void* const* d_in, const int* in_sizes, int n_in,
                              void* d_out, int out_size, void* d_ws, size_t ws_size,
                              hipStream_t stream) {
    const float* x        = (const float*)d_in[0];
    const int*   eidx     = (const int*)  d_in[1];
    const float* weight   = (const float*)d_in[2];
    const float* bias     = (const float*)d_in[3];
    const float* state_w  = (const float*)d_in[4];
    const float* state_b  = (const float*)d_in[5];
    const float* bn_gamma = (const float*)d_in[6];
    const float* bn_beta  = (const float*)d_in[7];

    float* sums = (float*)d_ws;                       // B*N*D
    float* cnt  = sums + (size_t)BB * NN * DD;        // N
    size_t zero_bytes = ((size_t)BB * NN * DD + NN) * sizeof(float);
    hipMemsetAsync(d_ws, 0, zero_bytes, stream);

    float* out_state = (float*)d_out;                 // B*N
    float* out_bn    = out_state + (size_t)BB * NN;   // B*N*D

    int edge_threads = EE * 64;
    edge_kernel<<<(edge_threads + 255) / 256, 256, 0, stream>>>(
        x, eidx, weight, bias, sums, cnt);

    int node_threads = NN * 64;
    node_kernel<<<(node_threads + 255) / 256, 256, 0, stream>>>(
        sums, cnt, state_w, state_b, bn_gamma, bn_beta, out_state, out_bn);
}